// Round 1
// baseline (343.292 us; speedup 1.0000x reference)
//
#include <hip/hip_runtime.h>
#include <stdint.h>
#include <math.h>

// Problem constants (B,L,H,D fixed by setup_inputs)
#define Bn 4
#define Ln 2048
#define Hn 8
#define Dn 64
#define BHn (Bn*Hn)
#define NTOP 40   // FACTOR * ceil(log(2048)) = 5*8
#define SK   40
#define NSAMP (Ln*SK)        // 81920

// ---------------- Threefry-2x32 (exact JAX replication) ----------------
__host__ __device__ inline uint32_t rotl32(uint32_t x, int r) {
  return (x << r) | (x >> (32 - r));
}

__host__ __device__ inline void tf2x32(uint32_t k0, uint32_t k1,
                                       uint32_t& x0, uint32_t& x1) {
  const uint32_t ks2 = k0 ^ k1 ^ 0x1BD11BDAu;
  const int RA[4] = {13, 15, 26, 6};
  const int RB[4] = {17, 29, 16, 24};
  x0 += k0; x1 += k1;
  for (int i = 0; i < 4; i++) { x0 += x1; x1 = rotl32(x1, RA[i]); x1 ^= x0; }
  x0 += k1;  x1 += ks2 + 1u;
  for (int i = 0; i < 4; i++) { x0 += x1; x1 = rotl32(x1, RB[i]); x1 ^= x0; }
  x0 += ks2; x1 += k0 + 2u;
  for (int i = 0; i < 4; i++) { x0 += x1; x1 = rotl32(x1, RA[i]); x1 ^= x0; }
  x0 += k0;  x1 += k1 + 3u;
  for (int i = 0; i < 4; i++) { x0 += x1; x1 = rotl32(x1, RB[i]); x1 ^= x0; }
  x0 += k1;  x1 += ks2 + 4u;
  for (int i = 0; i < 4; i++) { x0 += x1; x1 = rotl32(x1, RA[i]); x1 ^= x0; }
  x0 += ks2; x1 += k0 + 5u;
}

// jax_threefry_partitionable=True: elem n -> ctr (0, n); draw = out0 ^ out1
__device__ inline int draw2048(uint32_t k0, uint32_t k1, uint32_t n) {
  uint32_t a = 0u, b = n;
  tf2x32(k0, k1, a, b);
  return (int)((a ^ b) & (Ln - 1));
}

// ---------------- DPP 16-lane sum reduce (VALU pipe, zero DS ops) ----------------
// quad_perm xor1, quad_perm xor2, row_half_mirror, row_mirror -> full sum of the
// 16-lane row in every lane. Replaces 4x __shfl_xor (ds_bpermute) per reduce:
// moves work from the per-CU DS pipe (shared by 4 SIMDs) to per-SIMD VALU.
template<int CTRL>
__device__ __forceinline__ float dpp_add(float x) {
  int y = __builtin_amdgcn_update_dpp(0, __float_as_int(x), CTRL, 0xF, 0xF, true);
  return x + __int_as_float(y);
}
__device__ __forceinline__ float red16(float d) {
  d = dpp_add<0xB1>(d);   // quad_perm [1,0,3,2]  (xor 1)
  d = dpp_add<0x4E>(d);   // quad_perm [2,3,0,1]  (xor 2)
  d = dpp_add<0x141>(d);  // row_half_mirror      (pairs across 8-halves)
  d = dpp_add<0x140>(d);  // row_mirror           (pairs across 16-row)
  return d;
}

// ---------------- M = max_s(QK_s) - sum_s(QK_s)/L ----------------
// v3: quarter-wave-cooperative coalesced gather (proven) but with the DS-pipe
// saturation removed: (a) sample-index broadcast via a per-wg LDS table read
// as int4 (10 ds_read_b128 per 40 samples instead of 40 ds_bpermute), (b) the
// 16-lane dot reduce via DPP adds (VALU) instead of 4x shfl_xor (DS).
// DS instrs/wave: 200 -> ~13.
__global__ __launch_bounds__(256) void compute_M(const float* __restrict__ Q,
                                                 const float* __restrict__ K,
                                                 float* __restrict__ M,
                                                 uint32_t k0, uint32_t k1) {
  int xcd = blockIdx.x & 7;
  int idx = blockIdx.x >> 3;          // 0..511
  int bh  = (idx & 3) * 8 + xcd;      // {xcd, xcd+8, xcd+16, xcd+24}
  int seg = idx >> 2;                 // 0..127
  int tid = threadIdx.x;
  int qw  = tid >> 4;                 // query slot in wg: 0..15
  int j   = tid & 15;                 // lane within quarter-wave
  int i   = seg * 16 + qw;            // query index

  __shared__ alignas(16) int sidx[16][40];   // 2.5 KB sample-index table

  uint32_t n0 = (uint32_t)(i * SK);
  sidx[qw][j]      = draw2048(k0, k1, n0 + j);
  sidx[qw][16 + j] = draw2048(k0, k1, n0 + 16 + j);
  if (j < 8) sidx[qw][32 + j] = draw2048(k0, k1, n0 + 32 + j);

  const float* Qb = Q + ((size_t)bh * Ln + i) * Dn;
  float4 qf = ((const float4*)Qb)[j];
  __syncthreads();

  // pull all 40 indices into registers up front (compile-time indexed -> VGPRs)
  int4 I[10];
#pragma unroll
  for (int t = 0; t < 10; t++) I[t] = *(const int4*)&sidx[qw][t * 4];

  const float* Kb = K + (size_t)bh * Ln * Dn;
  float mx = -INFINITY, sm = 0.f;
#pragma unroll
  for (int t = 0; t < 10; t++) {
    int ls[4] = {I[t].x, I[t].y, I[t].z, I[t].w};
#pragma unroll
    for (int c = 0; c < 4; c++) {
      float4 kf = ((const float4*)(Kb + (size_t)ls[c] * Dn))[j];
      float d = qf.x * kf.x + qf.y * kf.y + qf.z * kf.z + qf.w * kf.w;
      d = red16(d);                    // full 64-elem dot in every lane
      mx = fmaxf(mx, d);
      sm += d;
    }
  }
  if (j == 0)
    M[(size_t)bh * Ln + i] = mx - sm * (1.0f / (float)Ln);
}

// ---------------- top-40, fused: one wg (4 waves) per bh ----------------
// Wave w: exact top-40 of its 512-element segment (8 vals/lane in regs,
// pure shfl argmax, global-index tie-break) -> LDS. Wave 0 merges the
// 4*40=160 candidates. Correct because the global top-40 elements are each
// inside their segment's top-40; tie-break lexicographic on global index
// matches jax.lax.top_k.
__global__ __launch_bounds__(256) void topk_fused(const float* __restrict__ M,
                                                  int* __restrict__ Mtop) {
  int bh = blockIdx.x;
  int tid = threadIdx.x, lane = tid & 63, w = tid >> 6;
  __shared__ float cv[4][NTOP];
  __shared__ int   ci[4][NTOP];
  {
    float cur[8];
    const float* m = M + (size_t)bh * Ln + w * 512;
#pragma unroll
    for (int j = 0; j < 8; j++) cur[j] = m[lane + 64 * j];
    for (int k = 0; k < NTOP; ++k) {
      float bv = cur[0]; int bj = 0;
#pragma unroll
      for (int j = 1; j < 8; j++)
        if (cur[j] > bv) { bv = cur[j]; bj = j; }  // ties keep smaller j
      int bi = w * 512 + lane + 64 * bj;           // bh-local global index
#pragma unroll
      for (int off = 1; off < 64; off <<= 1) {
        float ov = __shfl_xor(bv, off, 64);
        int   oi = __shfl_xor(bi, off, 64);
        if (ov > bv || (ov == bv && oi < bi)) { bv = ov; bi = oi; }
      }
      if (lane == 0) { cv[w][k] = bv; ci[w][k] = bi; }
      int ll  = bi & 63;
      int jj = (bi - w * 512) >> 6;
      if (lane == ll) cur[jj] = -INFINITY;
    }
  }
  __syncthreads();
  if (w == 0) {
    float cur[3]; int gix[3];
#pragma unroll
    for (int j = 0; j < 3; j++) {
      int c = lane + 64 * j;
      if (c < 160) { cur[j] = cv[c / NTOP][c % NTOP]; gix[j] = ci[c / NTOP][c % NTOP]; }
      else         { cur[j] = -INFINITY; gix[j] = 0x7fffffff; }
    }
    for (int k = 0; k < NTOP; ++k) {
      float bv = cur[0]; int bg = gix[0];
#pragma unroll
      for (int j = 1; j < 3; j++)
        if (cur[j] > bv || (cur[j] == bv && gix[j] < bg)) { bv = cur[j]; bg = gix[j]; }
#pragma unroll
      for (int off = 1; off < 64; off <<= 1) {
        float ov = __shfl_xor(bv, off, 64);
        int   og = __shfl_xor(bg, off, 64);
        if (ov > bv || (ov == bv && og < bg)) { bv = ov; bg = og; }
      }
      if (lane == 0) Mtop[bh * NTOP + k] = bg;
#pragma unroll
      for (int j = 0; j < 3; j++)
        if (gix[j] == bg) cur[j] = -INFINITY;
    }
  }
}

// ---------------- context cumsum, phase 1: per-tile (64 l) sums ----------------
__global__ __launch_bounds__(256) void vsum_partial(const float* __restrict__ V,
                                                    float* __restrict__ partial) {
  int tile = blockIdx.x & 31;
  int bh   = blockIdx.x >> 5;
  int d = threadIdx.x & 63;
  int g = threadIdx.x >> 6;
  const float* Vb = V + (size_t)bh * Ln * Dn;
  int l0 = tile * 64 + g * 16;
  float s = 0.f;
  for (int j = 0; j < 16; j++) s += Vb[(size_t)(l0 + j) * Dn + d];
  __shared__ float red[4][64];
  red[g][d] = s;
  __syncthreads();
  if (g == 0)
    partial[((size_t)bh * 32 + tile) * 64 + d] =
        red[0][d] + red[1][d] + red[2][d] + red[3][d];
}

// ---------------- context cumsum, phase 2: prefix + cumsum + transposed write ----------------
__global__ __launch_bounds__(256) void context_write(const float* __restrict__ V,
                                                     const float* __restrict__ partial,
                                                     float* __restrict__ out) {
  int tile = blockIdx.x & 31;
  int bh   = blockIdx.x >> 5;
  int b = bh >> 3, h = bh & 7;
  int d = threadIdx.x & 63;
  int g = threadIdx.x >> 6;
  __shared__ float red[4][64];
  float p = 0.f;
  for (int t = g; t < tile; t += 4)
    p += partial[((size_t)bh * 32 + t) * 64 + d];
  red[g][d] = p;
  __syncthreads();
  float prefix = red[0][d] + red[1][d] + red[2][d] + red[3][d];
  __syncthreads();
  const float* Vb = V + (size_t)bh * Ln * Dn;
  int l0 = tile * 64 + g * 16;
  float vloc[16]; float s = 0.f;
  for (int j = 0; j < 16; j++) {
    vloc[j] = Vb[(size_t)(l0 + j) * Dn + d];
    s += vloc[j];
  }
  red[g][d] = s;
  __syncthreads();
  float running = prefix;
  for (int gg = 0; gg < g; gg++) running += red[gg][d];
  for (int j = 0; j < 16; j++) {
    int l = l0 + j;
    running += vloc[j];
    out[(((size_t)b * Ln + l) * Hn + h) * Dn + d] =
        0.5f * ((float)(l + 1) * vloc[j] + running);
  }
}

// ---------------- sparse attention over the 40 selected rows ----------------
// v2: cooperative-row pass 1. Each quarter-wave owns whole K/Q rows (16 lanes
// x float4 = one 256 B row, perfectly coalesced, zero L1-thrash overfetch);
// the 5 selected Q/K rows live as LANE-RESIDENT float4 fragments (each lane
// only ever needs its own 16 B slice) -> pass-1 LDS reads drop from 160
// ds_read_b128/thread to ZERO. Per-(row,u) dot reduced with DPP (VALU pipe,
// not DS -- R8's shfl-reduce regression was DS-pipe saturation; DPP avoids
// it). sc padded to stride 2052 so pass 3 can read scores as float4
// (contiguous l) conflict-free. XCD swizzle: all 8 chunks of one bh share an
// XCD (K/Q/V L2-resident).
#define UC 5
#define SCS 2052   // 2048 + 4: float4-aligned, (u*2052)%32 = 4u -> conflict-free
__global__ __launch_bounds__(512, 2) void sparse_attn(const float* __restrict__ Q,
                                                      const float* __restrict__ K,
                                                      const float* __restrict__ V,
                                                      const int* __restrict__ Mtop,
                                                      float* __restrict__ out) {
  int xcd  = blockIdx.x & 7;
  int rest = blockIdx.x >> 3;     // 0..31
  int chunk = rest & 7;
  int bh    = (rest >> 3) * 8 + xcd;
  int b = bh >> 3, h = bh & 7;
  __shared__ alignas(16) float sc[UC][SCS];          // 40.1 KB scores->probs
  __shared__ alignas(16) float redp[8][UC][64];      // 10 KB partial attn@V
  __shared__ float inv_s[UC];
  const float* Qb = Q + (size_t)bh * Ln * Dn;
  const float* Kb = K + (size_t)bh * Ln * Dn;
  const float* Vb = V + (size_t)bh * Ln * Dn;
  int tid = threadIdx.x;
  int lane = tid & 63, w = tid >> 6;
  int l16 = tid & 15, qw = tid >> 4;   // quarter-wave id 0..31, lane-in-qw

  // selected rows: block-uniform -> scalar loads / SGPRs
  int rows[UC];
#pragma unroll
  for (int u = 0; u < UC; u++) rows[u] = Mtop[bh * NTOP + chunk * UC + u];

  // lane-resident fragments of the 5 selected Q/K rows (16 B per lane each)
  float4 qsel[UC], ksel[UC];
#pragma unroll
  for (int u = 0; u < UC; u++) {
    qsel[u] = *(const float4*)(Qb + (size_t)rows[u] * Dn + l16 * 4);
    ksel[u] = *(const float4*)(Kb + (size_t)rows[u] * Dn + l16 * 4);
  }
  // per-lane causal row (cndmask chain; rows[] stays statically indexed)
  int myrow = rows[0];
#pragma unroll
  for (int u = 1; u < UC; u++) if (l16 == u) myrow = rows[u];

  // pass 1: sc[u][r] = 0.0625*(Qsel[u].K[r] + Q[r].Ksel[u]), causal mask r>row
#pragma unroll 4
  for (int it = 0; it < 64; it++) {
    int r = it * 32 + qw;              // wave's 4 rows consecutive -> 1 KB/instr
    float4 kf = *(const float4*)(Kb + (size_t)r * Dn + l16 * 4);
    float4 qf = *(const float4*)(Qb + (size_t)r * Dn + l16 * 4);
    float keep = 0.f;
#pragma unroll
    for (int u = 0; u < UC; u++) {
      float d = qsel[u].x * kf.x + qsel[u].y * kf.y
              + qsel[u].z * kf.z + qsel[u].w * kf.w
              + ksel[u].x * qf.x + ksel[u].y * qf.y
              + ksel[u].z * qf.z + ksel[u].w * qf.w;
      d = red16(d);                    // 16-lane sum = full D=64 dot (x2 terms)
      if (l16 == u) keep = d;
    }
    if (l16 < UC)                      // banks (4*l16 + r)%32: conflict-free
      sc[l16][r] = (r > myrow) ? -1e9f : keep * 0.0625f;
  }
  __syncthreads();

  // pass 2: softmax per u; wave w handles u=w (waves 0..4)
  if (w < UC) {
    float mx = -INFINITY;
    for (int kq = 0; kq < 32; kq++) mx = fmaxf(mx, sc[w][lane + 64 * kq]);
    for (int off = 32; off; off >>= 1) mx = fmaxf(mx, __shfl_xor(mx, off, 64));
    float sum = 0.f;
    for (int kq = 0; kq < 32; kq++) {
      float e = __expf(sc[w][lane + 64 * kq] - mx);
      sc[w][lane + 64 * kq] = e;
      sum += e;
    }
    for (int off = 32; off; off >>= 1) sum += __shfl_xor(sum, off, 64);
    if (lane == 0) inv_s[w] = 1.0f / sum;
  }
  __syncthreads();

  // pass 3: attn @ V ; wave w owns l in [w*256, w*256+256) for ALL 5 u.
  // scores read as float4 over contiguous l (1 ds_read_b128 replaces 4 b32).
  {
    int quad = lane & 15, lr = lane >> 4;
    const float4* V4 = (const float4*)Vb;
    float4 a[UC];
#pragma unroll
    for (int u = 0; u < UC; u++) a[u] = make_float4(0.f, 0.f, 0.f, 0.f);
    for (int it4 = 0; it4 < 16; it4++) {
      int lb4 = w * 256 + it4 * 16 + lr * 4;
      float4 v0 = V4[(size_t)(lb4 + 0) * 16 + quad];
      float4 v1 = V4[(size_t)(lb4 + 1) * 16 + quad];
      float4 v2 = V4[(size_t)(lb4 + 2) * 16 + quad];
      float4 v3 = V4[(size_t)(lb4 + 3) * 16 + quad];
#pragma unroll
      for (int u = 0; u < UC; u++) {
        float4 s4 = *(const float4*)&sc[u][lb4];
        a[u].x += s4.x * v0.x + s4.y * v1.x + s4.z * v2.x + s4.w * v3.x;
        a[u].y += s4.x * v0.y + s4.y * v1.y + s4.z * v2.y + s4.w * v3.y;
        a[u].z += s4.x * v0.z + s4.y * v1.z + s4.z * v2.z + s4.w * v3.z;
        a[u].w += s4.x * v0.w + s4.y * v1.w + s4.z * v2.w + s4.w * v3.w;
      }
    }
#pragma unroll
    for (int u = 0; u < UC; u++) {
#pragma unroll
      for (int off = 16; off < 64; off <<= 1) {
        a[u].x += __shfl_xor(a[u].x, off, 64);
        a[u].y += __shfl_xor(a[u].y, off, 64);
        a[u].z += __shfl_xor(a[u].z, off, 64);
        a[u].w += __shfl_xor(a[u].w, off, 64);
      }
      if (lr == 0) *(float4*)(&redp[w][u][quad * 4]) = a[u];
    }
  }
  __syncthreads();

  if (w < UC) {
    // static-index row select for the epilogue (avoid rows[w] scratch)
    int erow = rows[0];
#pragma unroll
    for (int u = 1; u < UC; u++) if (w == u) erow = rows[u];
    float r = 0.f;
#pragma unroll
    for (int g = 0; g < 8; g++) r += redp[g][w][lane];
    float outv = 0.5f * (Vb[(size_t)erow * Dn + lane] + r * inv_s[w]);
    out[(((size_t)b * Ln + erow) * Hn + h) * Dn + lane] = outv;
  }
}

extern "C" void kernel_launch(void* const* d_in, const int* in_sizes, int n_in,
                              void* d_out, int out_size, void* d_ws, size_t ws_size,
                              hipStream_t stream) {
  const float* Q = (const float*)d_in[0];  // (B,L,H,D) flat == (B,H,L,D) reshape
  const float* K = (const float*)d_in[1];
  const float* V = (const float*)d_in[2];
  float* out = (float*)d_out;
  char* ws = (char*)d_ws;

  float* M       = (float*)(ws + NSAMP * 4);                       // 256 KB
  int*   Mtop    = (int*)(ws + NSAMP * 4 + BHn * Ln * 4);          // 5 KB
  float* partial = (float*)(ws + NSAMP * 4 + BHn * Ln * 4 + BHn * NTOP * 4); // 256 KB

  // Partitionable threefry split of key(42) = (0,42): k2 = tf(key, ctr=(0,1)).
  uint32_t s0 = 0u, s1 = 1u;
  tf2x32(0u, 42u, s0, s1);

  compute_M<<<4096, 256, 0, stream>>>(Q, K, M, s0, s1);
  topk_fused<<<BHn, 256, 0, stream>>>(M, Mtop);
  vsum_partial<<<BHn * 32, 256, 0, stream>>>(V, partial);
  context_write<<<BHn * 32, 256, 0, stream>>>(V, partial, out);
  sparse_attn<<<BHn * 8, 512, 0, stream>>>(Q, K, V, Mtop, out);
}

// Round 2
// 327.430 us; speedup vs baseline: 1.0484x; 1.0484x over previous
//
#include <hip/hip_runtime.h>
#include <stdint.h>
#include <math.h>

// Problem constants (B,L,H,D fixed by setup_inputs)
#define Bn 4
#define Ln 2048
#define Hn 8
#define Dn 64
#define BHn (Bn*Hn)
#define NTOP 40   // FACTOR * ceil(log(2048)) = 5*8
#define SK   40
#define NSAMP (Ln*SK)        // 81920

// ---------------- Threefry-2x32 (exact JAX replication) ----------------
__host__ __device__ inline uint32_t rotl32(uint32_t x, int r) {
  return (x << r) | (x >> (32 - r));
}

__host__ __device__ inline void tf2x32(uint32_t k0, uint32_t k1,
                                       uint32_t& x0, uint32_t& x1) {
  const uint32_t ks2 = k0 ^ k1 ^ 0x1BD11BDAu;
  const int RA[4] = {13, 15, 26, 6};
  const int RB[4] = {17, 29, 16, 24};
  x0 += k0; x1 += k1;
  for (int i = 0; i < 4; i++) { x0 += x1; x1 = rotl32(x1, RA[i]); x1 ^= x0; }
  x0 += k1;  x1 += ks2 + 1u;
  for (int i = 0; i < 4; i++) { x0 += x1; x1 = rotl32(x1, RB[i]); x1 ^= x0; }
  x0 += ks2; x1 += k0 + 2u;
  for (int i = 0; i < 4; i++) { x0 += x1; x1 = rotl32(x1, RA[i]); x1 ^= x0; }
  x0 += k0;  x1 += k1 + 3u;
  for (int i = 0; i < 4; i++) { x0 += x1; x1 = rotl32(x1, RB[i]); x1 ^= x0; }
  x0 += k1;  x1 += ks2 + 4u;
  for (int i = 0; i < 4; i++) { x0 += x1; x1 = rotl32(x1, RA[i]); x1 ^= x0; }
  x0 += ks2; x1 += k0 + 5u;
}

// jax_threefry_partitionable=True: elem n -> ctr (0, n); draw = out0 ^ out1
__device__ inline int draw2048(uint32_t k0, uint32_t k1, uint32_t n) {
  uint32_t a = 0u, b = n;
  tf2x32(k0, k1, a, b);
  return (int)((a ^ b) & (Ln - 1));
}

// ---------------- DPP 16-lane sum reduce (VALU pipe, zero DS ops) ----------------
// quad_perm xor1, quad_perm xor2, row_half_mirror, row_mirror -> full sum of the
// 16-lane row in every lane. Moves reduce work off the per-CU DS pipe (shared
// by 4 SIMDs) onto the per-SIMD VALU.
template<int CTRL>
__device__ __forceinline__ float dpp_add(float x) {
  int y = __builtin_amdgcn_update_dpp(0, __float_as_int(x), CTRL, 0xF, 0xF, true);
  return x + __int_as_float(y);
}
__device__ __forceinline__ float red16(float d) {
  d = dpp_add<0xB1>(d);   // quad_perm [1,0,3,2]  (xor 1)
  d = dpp_add<0x4E>(d);   // quad_perm [2,3,0,1]  (xor 2)
  d = dpp_add<0x141>(d);  // row_half_mirror      (pairs across 8-halves)
  d = dpp_add<0x140>(d);  // row_mirror           (pairs across 16-row)
  return d;
}

// ---------------- M = max_s(QK_s) - sum_s(QK_s)/L ----------------
// v3: quarter-wave-cooperative coalesced gather with DS-pipe saturation
// removed: (a) sample-index table in LDS read as int4 (10 ds_read_b128 per 40
// samples instead of 40 ds_bpermute), (b) 16-lane dot reduce via DPP (VALU)
// instead of 4x shfl_xor (DS). DS instrs/wave: 200 -> ~13.
__global__ __launch_bounds__(256) void compute_M(const float* __restrict__ Q,
                                                 const float* __restrict__ K,
                                                 float* __restrict__ M,
                                                 uint32_t k0, uint32_t k1) {
  int xcd = blockIdx.x & 7;
  int idx = blockIdx.x >> 3;          // 0..511
  int bh  = (idx & 3) * 8 + xcd;      // {xcd, xcd+8, xcd+16, xcd+24}
  int seg = idx >> 2;                 // 0..127
  int tid = threadIdx.x;
  int qw  = tid >> 4;                 // query slot in wg: 0..15
  int j   = tid & 15;                 // lane within quarter-wave
  int i   = seg * 16 + qw;            // query index

  __shared__ alignas(16) int sidx[16][40];   // 2.5 KB sample-index table

  uint32_t n0 = (uint32_t)(i * SK);
  sidx[qw][j]      = draw2048(k0, k1, n0 + j);
  sidx[qw][16 + j] = draw2048(k0, k1, n0 + 16 + j);
  if (j < 8) sidx[qw][32 + j] = draw2048(k0, k1, n0 + 32 + j);

  const float* Qb = Q + ((size_t)bh * Ln + i) * Dn;
  float4 qf = ((const float4*)Qb)[j];
  __syncthreads();

  // pull all 40 indices into registers up front (compile-time indexed -> VGPRs)
  int4 I[10];
#pragma unroll
  for (int t = 0; t < 10; t++) I[t] = *(const int4*)&sidx[qw][t * 4];

  const float* Kb = K + (size_t)bh * Ln * Dn;
  float mx = -INFINITY, sm = 0.f;
#pragma unroll
  for (int t = 0; t < 10; t++) {
    int ls[4] = {I[t].x, I[t].y, I[t].z, I[t].w};
#pragma unroll
    for (int c = 0; c < 4; c++) {
      float4 kf = ((const float4*)(Kb + (size_t)ls[c] * Dn))[j];
      float d = qf.x * kf.x + qf.y * kf.y + qf.z * kf.z + qf.w * kf.w;
      d = red16(d);                    // full 64-elem dot in every lane
      mx = fmaxf(mx, d);
      sm += d;
    }
  }
  if (j == 0)
    M[(size_t)bh * Ln + i] = mx - sm * (1.0f / (float)Ln);
}

// ---------------- top-40, fused: one wg (4 waves) per bh ----------------
__global__ __launch_bounds__(256) void topk_fused(const float* __restrict__ M,
                                                  int* __restrict__ Mtop) {
  int bh = blockIdx.x;
  int tid = threadIdx.x, lane = tid & 63, w = tid >> 6;
  __shared__ float cv[4][NTOP];
  __shared__ int   ci[4][NTOP];
  {
    float cur[8];
    const float* m = M + (size_t)bh * Ln + w * 512;
#pragma unroll
    for (int j = 0; j < 8; j++) cur[j] = m[lane + 64 * j];
    for (int k = 0; k < NTOP; ++k) {
      float bv = cur[0]; int bj = 0;
#pragma unroll
      for (int j = 1; j < 8; j++)
        if (cur[j] > bv) { bv = cur[j]; bj = j; }  // ties keep smaller j
      int bi = w * 512 + lane + 64 * bj;           // bh-local global index
#pragma unroll
      for (int off = 1; off < 64; off <<= 1) {
        float ov = __shfl_xor(bv, off, 64);
        int   oi = __shfl_xor(bi, off, 64);
        if (ov > bv || (ov == bv && oi < bi)) { bv = ov; bi = oi; }
      }
      if (lane == 0) { cv[w][k] = bv; ci[w][k] = bi; }
      int ll  = bi & 63;
      int jj = (bi - w * 512) >> 6;
      if (lane == ll) cur[jj] = -INFINITY;
    }
  }
  __syncthreads();
  if (w == 0) {
    float cur[3]; int gix[3];
#pragma unroll
    for (int j = 0; j < 3; j++) {
      int c = lane + 64 * j;
      if (c < 160) { cur[j] = cv[c / NTOP][c % NTOP]; gix[j] = ci[c / NTOP][c % NTOP]; }
      else         { cur[j] = -INFINITY; gix[j] = 0x7fffffff; }
    }
    for (int k = 0; k < NTOP; ++k) {
      float bv = cur[0]; int bg = gix[0];
#pragma unroll
      for (int j = 1; j < 3; j++)
        if (cur[j] > bv || (cur[j] == bv && gix[j] < bg)) { bv = cur[j]; bg = gix[j]; }
#pragma unroll
      for (int off = 1; off < 64; off <<= 1) {
        float ov = __shfl_xor(bv, off, 64);
        int   og = __shfl_xor(bg, off, 64);
        if (ov > bv || (ov == bv && og < bg)) { bv = ov; bg = og; }
      }
      if (lane == 0) Mtop[bh * NTOP + k] = bg;
#pragma unroll
      for (int j = 0; j < 3; j++)
        if (gix[j] == bg) cur[j] = -INFINITY;
    }
  }
}

// ---------------- context cumsum, phase 1: per-tile (64 l) sums ----------------
__global__ __launch_bounds__(256) void vsum_partial(const float* __restrict__ V,
                                                    float* __restrict__ partial) {
  int tile = blockIdx.x & 31;
  int bh   = blockIdx.x >> 5;
  int d = threadIdx.x & 63;
  int g = threadIdx.x >> 6;
  const float* Vb = V + (size_t)bh * Ln * Dn;
  int l0 = tile * 64 + g * 16;
  float s = 0.f;
  for (int j = 0; j < 16; j++) s += Vb[(size_t)(l0 + j) * Dn + d];
  __shared__ float red[4][64];
  red[g][d] = s;
  __syncthreads();
  if (g == 0)
    partial[((size_t)bh * 32 + tile) * 64 + d] =
        red[0][d] + red[1][d] + red[2][d] + red[3][d];
}

// ---------------- context cumsum, phase 2: prefix + cumsum + transposed write ----------------
__global__ __launch_bounds__(256) void context_write(const float* __restrict__ V,
                                                     const float* __restrict__ partial,
                                                     float* __restrict__ out) {
  int tile = blockIdx.x & 31;
  int bh   = blockIdx.x >> 5;
  int b = bh >> 3, h = bh & 7;
  int d = threadIdx.x & 63;
  int g = threadIdx.x >> 6;
  __shared__ float red[4][64];
  float p = 0.f;
  for (int t = g; t < tile; t += 4)
    p += partial[((size_t)bh * 32 + t) * 64 + d];
  red[g][d] = p;
  __syncthreads();
  float prefix = red[0][d] + red[1][d] + red[2][d] + red[3][d];
  __syncthreads();
  const float* Vb = V + (size_t)bh * Ln * Dn;
  int l0 = tile * 64 + g * 16;
  float vloc[16]; float s = 0.f;
  for (int j = 0; j < 16; j++) {
    vloc[j] = Vb[(size_t)(l0 + j) * Dn + d];
    s += vloc[j];
  }
  red[g][d] = s;
  __syncthreads();
  float running = prefix;
  for (int gg = 0; gg < g; gg++) running += red[gg][d];
  for (int j = 0; j < 16; j++) {
    int l = l0 + j;
    running += vloc[j];
    out[(((size_t)b * Ln + l) * Hn + h) * Dn + d] =
        0.5f * ((float)(l + 1) * vloc[j] + running);
  }
}

// ---------------- sparse attention over the 40 selected rows ----------------
// v3: cooperative-row pass 1 (R1 design) with the register-spill fixed.
// R1's WRITE_SIZE=177MB / FETCH=208MB was scratch spill: unroll-4 kept 32
// load-VGPRs in flight on top of 40 persistent qsel/ksel VGPRs, exceeding the
// 128-VGPR allocation with spill code inside the 64-iter loop. Fix: explicit
// depth-1 prefetch (16 load VGPRs live) and no launch-bounds VGPR clamp.
// Each quarter-wave owns whole K/Q rows (16 lanes x float4 = one 256 B row,
// perfectly coalesced, each row read ONCE per block -> 1 MB L2/block vs the
// old 4 MB); selected Q/K rows are lane-resident float4 fragments (zero
// pass-1 LDS traffic); per-(row,u) dot reduced with DPP (VALU pipe, not DS).
#define UC 5
#define SCS 2052   // 2048 + 4: float4-aligned, (u*2052)%32 = 4u -> conflict-free
__global__ __launch_bounds__(512) void sparse_attn(const float* __restrict__ Q,
                                                   const float* __restrict__ K,
                                                   const float* __restrict__ V,
                                                   const int* __restrict__ Mtop,
                                                   float* __restrict__ out) {
  int xcd  = blockIdx.x & 7;
  int rest = blockIdx.x >> 3;     // 0..31
  int chunk = rest & 7;
  int bh    = (rest >> 3) * 8 + xcd;
  int b = bh >> 3, h = bh & 7;
  __shared__ alignas(16) float sc[UC][SCS];          // 40.1 KB scores->probs
  __shared__ alignas(16) float redp[8][UC][64];      // 10 KB partial attn@V
  __shared__ float inv_s[UC];
  const float* Qb = Q + (size_t)bh * Ln * Dn;
  const float* Kb = K + (size_t)bh * Ln * Dn;
  const float* Vb = V + (size_t)bh * Ln * Dn;
  int tid = threadIdx.x;
  int lane = tid & 63, w = tid >> 6;
  int l16 = tid & 15, qw = tid >> 4;   // lane-in-qw, quarter-wave id 0..31

  // selected rows: block-uniform address -> s_load / SGPRs
  int rows[UC];
#pragma unroll
  for (int u = 0; u < UC; u++) rows[u] = Mtop[bh * NTOP + chunk * UC + u];

  // lane-resident fragments of the 5 selected Q/K rows (16 B per lane each)
  float4 qsel[UC], ksel[UC];
#pragma unroll
  for (int u = 0; u < UC; u++) {
    qsel[u] = *(const float4*)(Qb + (size_t)rows[u] * Dn + l16 * 4);
    ksel[u] = *(const float4*)(Kb + (size_t)rows[u] * Dn + l16 * 4);
  }
  // per-lane causal row (cndmask chain; rows[] stays statically indexed)
  int myrow = rows[0];
#pragma unroll
  for (int u = 1; u < UC; u++) if (l16 == u) myrow = rows[u];

  // pass 1: sc[u][r] = 0.0625*(Qsel[u].K[r] + Q[r].Ksel[u]), causal mask r>row
  // depth-1 prefetch: only kf,qf,kn,qn (16 VGPRs) of load data live at once.
  {
    float4 kf = *(const float4*)(Kb + (size_t)qw * Dn + l16 * 4);
    float4 qf = *(const float4*)(Qb + (size_t)qw * Dn + l16 * 4);
    for (int it = 0; it < 64; it++) {
      int r = it * 32 + qw;            // wave's 4 rows consecutive -> 1 KB/instr
      float4 kn, qn;
      if (it < 63) {
        kn = *(const float4*)(Kb + (size_t)(r + 32) * Dn + l16 * 4);
        qn = *(const float4*)(Qb + (size_t)(r + 32) * Dn + l16 * 4);
      }
      float keep = 0.f;
#pragma unroll
      for (int u = 0; u < UC; u++) {
        float d = qsel[u].x * kf.x + qsel[u].y * kf.y
                + qsel[u].z * kf.z + qsel[u].w * kf.w
                + ksel[u].x * qf.x + ksel[u].y * qf.y
                + ksel[u].z * qf.z + ksel[u].w * qf.w;
        d = red16(d);                  // 16-lane sum = full D=64 dot (x2 terms)
        if (l16 == u) keep = d;
      }
      if (l16 < UC)                    // banks (4*l16 + r)%32: conflict-free
        sc[l16][r] = (r > myrow) ? -1e9f : keep * 0.0625f;
      if (it < 63) { kf = kn; qf = qn; }
    }
  }
  __syncthreads();

  // pass 2: softmax per u; wave w handles u=w (waves 0..4)
  if (w < UC) {
    float mx = -INFINITY;
    for (int kq = 0; kq < 32; kq++) mx = fmaxf(mx, sc[w][lane + 64 * kq]);
    for (int off = 32; off; off >>= 1) mx = fmaxf(mx, __shfl_xor(mx, off, 64));
    float sum = 0.f;
    for (int kq = 0; kq < 32; kq++) {
      float e = __expf(sc[w][lane + 64 * kq] - mx);
      sc[w][lane + 64 * kq] = e;
      sum += e;
    }
    for (int off = 32; off; off >>= 1) sum += __shfl_xor(sum, off, 64);
    if (lane == 0) inv_s[w] = 1.0f / sum;
  }
  __syncthreads();

  // pass 3: attn @ V ; wave w owns l in [w*256, w*256+256) for ALL 5 u.
  // scores read as float4 over contiguous l (1 ds_read_b128 replaces 4 b32).
  {
    int quad = lane & 15, lr = lane >> 4;
    const float4* V4 = (const float4*)Vb;
    float4 a[UC];
#pragma unroll
    for (int u = 0; u < UC; u++) a[u] = make_float4(0.f, 0.f, 0.f, 0.f);
    for (int it4 = 0; it4 < 16; it4++) {
      int lb4 = w * 256 + it4 * 16 + lr * 4;
      float4 v0 = V4[(size_t)(lb4 + 0) * 16 + quad];
      float4 v1 = V4[(size_t)(lb4 + 1) * 16 + quad];
      float4 v2 = V4[(size_t)(lb4 + 2) * 16 + quad];
      float4 v3 = V4[(size_t)(lb4 + 3) * 16 + quad];
#pragma unroll
      for (int u = 0; u < UC; u++) {
        float4 s4 = *(const float4*)&sc[u][lb4];
        a[u].x += s4.x * v0.x + s4.y * v1.x + s4.z * v2.x + s4.w * v3.x;
        a[u].y += s4.x * v0.y + s4.y * v1.y + s4.z * v2.y + s4.w * v3.y;
        a[u].z += s4.x * v0.z + s4.y * v1.z + s4.z * v2.z + s4.w * v3.z;
        a[u].w += s4.x * v0.w + s4.y * v1.w + s4.z * v2.w + s4.w * v3.w;
      }
    }
#pragma unroll
    for (int u = 0; u < UC; u++) {
#pragma unroll
      for (int off = 16; off < 64; off <<= 1) {
        a[u].x += __shfl_xor(a[u].x, off, 64);
        a[u].y += __shfl_xor(a[u].y, off, 64);
        a[u].z += __shfl_xor(a[u].z, off, 64);
        a[u].w += __shfl_xor(a[u].w, off, 64);
      }
      if (lr == 0) *(float4*)(&redp[w][u][quad * 4]) = a[u];
    }
  }
  __syncthreads();

  if (w < UC) {
    // static-index row select for the epilogue (avoid rows[w] scratch)
    int erow = rows[0];
#pragma unroll
    for (int u = 1; u < UC; u++) if (w == u) erow = rows[u];
    float r = 0.f;
#pragma unroll
    for (int g = 0; g < 8; g++) r += redp[g][w][lane];
    float outv = 0.5f * (Vb[(size_t)erow * Dn + lane] + r * inv_s[w]);
    out[(((size_t)b * Ln + erow) * Hn + h) * Dn + lane] = outv;
  }
}

extern "C" void kernel_launch(void* const* d_in, const int* in_sizes, int n_in,
                              void* d_out, int out_size, void* d_ws, size_t ws_size,
                              hipStream_t stream) {
  const float* Q = (const float*)d_in[0];  // (B,L,H,D) flat == (B,H,L,D) reshape
  const float* K = (const float*)d_in[1];
  const float* V = (const float*)d_in[2];
  float* out = (float*)d_out;
  char* ws = (char*)d_ws;

  float* M       = (float*)(ws + NSAMP * 4);                       // 256 KB
  int*   Mtop    = (int*)(ws + NSAMP * 4 + BHn * Ln * 4);          // 5 KB
  float* partial = (float*)(ws + NSAMP * 4 + BHn * Ln * 4 + BHn * NTOP * 4); // 256 KB

  // Partitionable threefry split of key(42) = (0,42): k2 = tf(key, ctr=(0,1)).
  uint32_t s0 = 0u, s1 = 1u;
  tf2x32(0u, 42u, s0, s1);

  compute_M<<<4096, 256, 0, stream>>>(Q, K, M, s0, s1);
  topk_fused<<<BHn, 256, 0, stream>>>(M, Mtop);
  vsum_partial<<<BHn * 32, 256, 0, stream>>>(V, partial);
  context_write<<<BHn * 32, 256, 0, stream>>>(V, partial, out);
  sparse_attn<<<BHn * 8, 512, 0, stream>>>(Q, K, V, Mtop, out);
}